// Round 12
// baseline (206.327 us; speedup 1.0000x reference)
//
#include <hip/hip_runtime.h>
#include <hip/hip_bf16.h>

#define SEQ   4096
#define DIM   768
#define HEADS 12
#define NQKV  2304
// Q pre-scaled by 0.125*log2(e) in QKV epilogue -> p = 2^st = exp(score/8)
#define QSCALE 0.18033688011f

#if __has_builtin(__builtin_amdgcn_exp2f)
#define EXP2(x) __builtin_amdgcn_exp2f(x)
#else
#define EXP2(x) __expf((x) * 0.69314718056f)
#endif

typedef __bf16 bf16_t;
typedef bf16_t bf16x8 __attribute__((ext_vector_type(8)));
typedef float  f32x4  __attribute__((ext_vector_type(4)));
typedef float  f32x16 __attribute__((ext_vector_type(16)));
typedef unsigned short u16;
typedef unsigned int   u32;

static __device__ __forceinline__ float bf2f(u16 v) {
    union { float f; unsigned u; } x; x.u = ((unsigned)v) << 16; return x.f;
}
static __device__ __forceinline__ u16 f2bf(float f) {
    union { float f; unsigned u; } x; x.f = f;
    unsigned r = x.u + 0x7fff + ((x.u >> 16) & 1);   // RNE
    return (u16)(r >> 16);
}
static __device__ __forceinline__ u32 fbits(float f) {
    union { float f; unsigned u; } x; x.f = f; return x.u;
}
static __device__ __forceinline__ void gload_lds16(const u16* g, u16* l) {
    __builtin_amdgcn_global_load_lds(
        (const __attribute__((address_space(1))) unsigned int*)g,
        (__attribute__((address_space(3))) unsigned int*)l, 16, 0, 0);
}

// per-block dtype self-detection (x fp32 vs bf16)
static __device__ __forceinline__ int detect_f32(const u32* __restrict__ x) {
    int lane = threadIdx.x & 63;
    int cnt = 0;
#pragma unroll
    for (int i = 0; i < 8; ++i) {
        u32 w = x[lane * 8 + i];
        cnt += (((w >> 7) & 0xFF) >= 0x8F) ? 1 : 0;
    }
#pragma unroll
    for (int m = 1; m < 64; m <<= 1) cnt += __shfl_xor(cnt, m);
    return cnt >= 64;
}

// ---- fused prep: [0,432) transpose w_qkv; [432,576) transpose w_proj; rest convert x+biases
__global__ __launch_bounds__(256) void prep(
    const void* __restrict__ x, const void* __restrict__ wqkv,
    const void* __restrict__ bqkv, const void* __restrict__ wproj,
    const void* __restrict__ bproj,
    u16* __restrict__ cvt, u16* __restrict__ wqkvT, u16* __restrict__ wprojT)
{
    __shared__ u16 tile[64][65];
    const bool f32 = detect_f32((const u32*)x) != 0;
    const int b = blockIdx.x;
    const int t = threadIdx.x;

    if (b < 576) {
        const void* src; u16* dst; int K, N, tx, ty;
        if (b < 432) { src = wqkv; dst = wqkvT; K = DIM; N = NQKV; tx = b % 36; ty = b / 36; }
        else { int bb = b - 432; src = wproj; dst = wprojT; K = DIM; N = DIM; tx = bb % 12; ty = bb / 12; }
        const int k0 = ty * 64, n0 = tx * 64;
#pragma unroll
        for (int i = 0; i < 16; ++i) {
            int idx = i * 256 + t;
            int r = idx >> 6, c = idx & 63;
            size_t si = (size_t)(k0 + r) * N + n0 + c;
            tile[r][c] = f32 ? f2bf(((const float*)src)[si]) : ((const u16*)src)[si];
        }
        __syncthreads();
#pragma unroll
        for (int i = 0; i < 16; ++i) {
            int idx = i * 256 + t;
            int r = idx >> 6, c = idx & 63;
            dst[(size_t)(n0 + r) * K + k0 + c] = tile[c][r];
        }
    } else {
        const int SX = SEQ * DIM, e1 = SX + NQKV;
        const int n_cvt = e1 + DIM;
        for (int i = (b - 576) * 256 + t; i < n_cvt; i += 200 * 256) {
            const void* s; int off;
            if      (i < SX) { s = x; off = i; }
            else if (i < e1) { s = bqkv; off = i - SX; }
            else             { s = bproj; off = i - e1; }
            cvt[i] = f32 ? f2bf(((const float*)s)[off]) : ((const u16*)s)[off];
        }
    }
}

// ---- m97-style GEMM, tile-size-templated: C[M,N] = A[M,K] @ BT[N,K]^T + bias[N]
// MODE 0: out dtype per self-detect (fp32 Cf / bf16 C0).
// MODE 1 (QKV): n<768 Q*QSCALE; n<1536 K; n>=1536 V -> coalesced
//   transpose-via-LDS into VT (sigma-permuted m).
// R14: counted-vmcnt 3-buffer K-loop (verified -21us). R15: T1 XCD remap.
// R18: gemm1 runs BM=64 x BN=128 -> 1152 blocks, 36KB LDS -> 4 blocks/CU
// resident, 4.5/CU avg (max-work-CU 1.11x ideal vs 1.33x at 576-block 128²
// where 64 CUs carried 3 blocks and 192 carried 2). gemm2 back at 128²
// (R10 best-measured; R11's 64² was noise-negative). Same BK=32
// K-accumulation order -> bit-identical output.
template<int MODE, int BM, int BN>
__global__ __launch_bounds__(256) void gemm128(
    const u16* __restrict__ A, const u16* __restrict__ BT, const u16* __restrict__ bias,
    u16* __restrict__ C0, float* __restrict__ Cf, u16* __restrict__ VT,
    const u32* __restrict__ xdet, int M, int N, int K)
{
    constexpr int WM  = BM / 2;            // per-wave output rows
    constexpr int WN  = BN / 2;            // per-wave output cols
    constexpr int NI  = WM / 16;           // m-frags per wave
    constexpr int NJ  = WN / 16;           // n-frags per wave
    constexpr int ARW = BM / 4;            // A stage rows per wave
    constexpr int BRW = BN / 4;            // B stage rows per wave
    constexpr int LPS = (BM + BN) / 64;    // gloads per stage per wave
    constexpr int TSTR = BM + 8;           // V-transpose LDS row stride (u16)

    __shared__ union SharedLds {
        struct { u16 a[3][BM * 32]; u16 b[3][BN * 32]; } s;     // 3-buffer staging
        u16 t[(MODE == 1) ? 128 * TSTR : 1];                     // V-transpose (MODE 1)
    } lds;

    const int t    = threadIdx.x;
    const int w    = t >> 6;
    const int lane = t & 63;
    const int l15  = lane & 15;
    const int quad = lane >> 4;
    const int wm   = w >> 1, wn = w & 1;

    // T1 XCD-bijective remap (nwg % 8 == 0 for all GEMM grids here)
    const int lin     = blockIdx.y * gridDim.x + blockIdx.x;
    const int cpx     = (gridDim.x * gridDim.y) >> 3;
    const int logical = (lin & 7) * cpx + (lin >> 3);
    const int m0 = (logical / gridDim.x) * BM;
    const int n0 = (logical % gridDim.x) * BN;

    const int kch = (lane & 3) * 8;
    const u16* asrc = A  + (size_t)(m0 + w * ARW + (lane >> 2)) * K + kch;
    const u16* bsrc = BT + (size_t)(n0 + w * BRW + (lane >> 2)) * K + kch;
    const int woffA = w * ARW * 32;
    const int woffB = w * BRW * 32;

    f32x4 acc[NI][NJ] = {};

    u16 *aA = lds.s.a[0], *aB = lds.s.a[1], *aC = lds.s.a[2];
    u16 *bA = lds.s.b[0], *bB = lds.s.b[1], *bC = lds.s.b[2];

    auto STAGE = [&](u16* ad, u16* bd) {
#pragma unroll
        for (int s = 0; s < BM / 64; ++s)
            gload_lds16(asrc + s * 16 * K, ad + woffA + s * 16 * 32);
#pragma unroll
        for (int s = 0; s < BN / 64; ++s)
            gload_lds16(bsrc + s * 16 * K, bd + woffB + s * 16 * 32);
        asrc += 32; bsrc += 32;
    };
    auto COMPUTE = [&](const u16* ab_, const u16* bb_) {
        const u16* ab = ab_ + (wm * WM + l15) * 32 + quad * 8;
        const u16* bb = bb_ + (wn * WN + l15) * 32 + quad * 8;
        bf16x8 af[NI], bfr[NJ];
#pragma unroll
        for (int i = 0; i < NI; ++i) af[i]  = *(const bf16x8*)(ab + i * 16 * 32);
#pragma unroll
        for (int j = 0; j < NJ; ++j) bfr[j] = *(const bf16x8*)(bb + j * 16 * 32);
#pragma unroll
        for (int i = 0; i < NI; ++i)
#pragma unroll
            for (int j = 0; j < NJ; ++j)
                acc[i][j] = __builtin_amdgcn_mfma_f32_16x16x32_bf16(af[i], bfr[j], acc[i][j], 0, 0, 0);
    };
    auto WAIT_LPS = [&]() {
        if constexpr (LPS == 4)      asm volatile("s_waitcnt vmcnt(4)" ::: "memory");
        else if constexpr (LPS == 3) asm volatile("s_waitcnt vmcnt(3)" ::: "memory");
        else                         asm volatile("s_waitcnt vmcnt(2)" ::: "memory");
    };

    const int NK = K >> 5;          // 24 for K=768
    STAGE(aA, bA);                  // tile 0
    STAGE(aB, bB);                  // tile 1
    for (int kt = 0; kt < NK - 2; ++kt) {
        // outstanding (oldest first): stage(kt)(LPS), stage(kt+1)(LPS)
        WAIT_LPS();                 // drain stage(kt)
        __builtin_amdgcn_s_barrier();
        STAGE(aC, bC);              // tile kt+2 (overwrites buffer read at kt-1)
        COMPUTE(aA, bA);            // tile kt
        { u16* tt = aA; aA = aB; aB = aC; aC = tt; }
        { u16* tt = bA; bA = bB; bB = bC; bC = tt; }
    }
    // tile NK-2: drain its stage, keep stage(NK-1) in flight
    WAIT_LPS();
    __builtin_amdgcn_s_barrier();
    COMPUTE(aA, bA);
    { u16* tt = aA; aA = aB; aB = aC; aC = tt; }
    { u16* tt = bA; bA = bB; bB = bC; bC = tt; }
    // tile NK-1: drain everything
    asm volatile("s_waitcnt vmcnt(0)" ::: "memory");
    __builtin_amdgcn_s_barrier();
    COMPUTE(aA, bA);

    if constexpr (MODE == 1) {
        if (n0 >= 1536) {
            // V transpose-via-LDS epilogue (coalesced stores). Staging buffers
            // are dead after the loop; lds.t aliases them — barrier first.
            __syncthreads();
#pragma unroll
            for (int i = 0; i < NI; ++i)
#pragma unroll
                for (int j = 0; j < NJ; ++j)
#pragma unroll
                    for (int r = 0; r < 4; ++r) {
                        int ml = wm * WM + i * 16 + quad * 4 + r;
                        int nl = wn * WN + j * 16 + l15;
                        int mpl = (ml & ~15) | (ml & 3) |
                                  (((ml >> 2) & 1) << 3) | (((ml >> 3) & 1) << 2);
                        float v = acc[i][j][r] + bf2f(bias[n0 + nl]);
                        lds.t[nl * TSTR + mpl] = f2bf(v);
                    }
            __syncthreads();
            // coalesced writeout: BM/8 lanes cover one row's BM*2B segment
            constexpr int LPR = BM / 8;         // lanes per row
            constexpr int RPP = 256 / LPR;      // rows per pass
            const int rr = t / LPR;
            const int mo = (t % LPR) * 8;
#pragma unroll
            for (int it = 0; it < 128 / RPP; ++it) {
                int nl = rr + it * RPP;
                *(bf16x8*)(VT + (size_t)(n0 - 1536 + nl) * SEQ + m0 + mo) =
                    *(const bf16x8*)(lds.t + nl * TSTR + mo);
            }
            return;
        }
    }

    bool outf32 = false;
    if (MODE == 0) outf32 = detect_f32(xdet) != 0;
#pragma unroll
    for (int i = 0; i < NI; ++i)
#pragma unroll
        for (int j = 0; j < NJ; ++j)
#pragma unroll
            for (int r = 0; r < 4; ++r) {
                int m = m0 + wm * WM + i * 16 + quad * 4 + r;
                int n = n0 + wn * WN + j * 16 + l15;
                float v = acc[i][j][r] + bf2f(bias[n]);
                if (MODE == 0) {
                    if (outf32) Cf[(size_t)m * N + n] = v;
                    else        C0[(size_t)m * N + n] = f2bf(v);
                } else {
                    // Q/K blocks only (V returned above)
                    float s = (n < 768) ? v * QSCALE : v;
                    C0[(size_t)m * 1536 + n] = f2bf(s);
                }
            }
}

// ---- Flash attention. Block = (64 q, head). 4 waves = (q-half wq) x (key-half wk).
// S^T = K x Q^T; sigma-permuted V^T makes S^T C-regs directly the PV A-fragment.
// p = 2^st (Q pre-scaled by QSCALE). Row-sums via ones-MFMA on the SAME
// packed/truncated P fragment (consistent normalization).
// Verified config (72-74us): launch_bounds(256,3) — register-limited at 3
// waves/SIMD (~76 arch VGPR + ~80 accumulator regs in the unified file);
// forcing 4 spills (R15: WRITE_SIZE 6MB->40MB). T15 st ping-pong, 3-buffer
// counted-vmcnt staging, XCD-bijective remap, s_setprio on MFMA clusters.
// Bank-conflict counter (~6.3M) verified benign: 2-way aliasing (64 lanes /
// 32 banks) which m136 shows is free; R2 halved the count with no speedup.
__global__ __launch_bounds__(256, 3) void attn_kernel(
    const u16* __restrict__ qk, const u16* __restrict__ vt, u16* __restrict__ out)
{
    __shared__ u16 k_lds[3][64 * 64];
    __shared__ u16 v_lds[3][64 * 64];
    __shared__ float l_red[2][2][32];   // [wq][wk][q]

    const int t    = threadIdx.x;
    const int w    = t >> 6;
    const int lane = t & 63;
    const int l31  = lane & 31;
    const int h    = lane >> 5;
    const int wq   = w & 1;
    const int wk   = w >> 1;

    // XCD-aware bijective remap (R1: FETCH 52MB -> 11.3MB).
    const int lin     = blockIdx.x + (blockIdx.y << 6);       // 0..767
    const int logical = (lin & 7) * 96 + (lin >> 3);
    const int head    = logical >> 6;
    const int q0      = (logical & 63) * 64 + wq * 32;

    // Q B-frags: q = q0+l31, d = h*8+16s+j (Q pre-scaled by QSCALE)
    const u16* qrow = qk + (size_t)(q0 + l31) * 1536 + head * 64 + h * 8;
    bf16x8 qb[4];
#pragma unroll
    for (int s = 0; s < 4; ++s) qb[s] = *(const bf16x8*)(qrow + 16 * s);

    bf16x8 ones;
#pragma unroll
    for (int j = 0; j < 8; ++j) ones[j] = (bf16_t)1.0f;

    const f32x16 fz = {};   // persistent zero C-operand for the first QK MFMA

    // staging: lane -> row 8w+(lane>>3), stored chunk lane&7 = logical chunk cs
    const int srow = 8 * w + (lane >> 3);
    const int cs   = ((lane & 7) - srow) & 7;
    const u16* kst0 = qk + 768 + head * 64 + (size_t)srow * 1536 + cs * 8;
    const u16* kst1 = kst0 + (size_t)32 * 1536;
    const u16* vst0 = vt + (size_t)head * 64 * SEQ + (size_t)srow * SEQ + cs * 8;
    const u16* vst1 = vst0 + (size_t)32 * SEQ;
    const int woff = 8 * w * 64;

    const int krow = 32 * wk + l31;

    f32x16 o0 = {}, o1 = {}, lac = {};

    auto SK = [&](u16* kd) {
        gload_lds16(kst0, kd + woff);
        gload_lds16(kst1, kd + woff + 32 * 64);
        kst0 += (size_t)64 * 1536;
        kst1 += (size_t)64 * 1536;
    };
    auto SV = [&](u16* vd) {
        gload_lds16(vst0, vd + woff);
        gload_lds16(vst1, vd + woff + 32 * 64);
        vst0 += 64;
        vst1 += 64;
    };

    // QK^T for one 64-key tile: 4 MFMA, returns S^T C-regs.
    auto QK = [&](const u16* kb) -> f32x16 {
        const u16* kbase = kb + krow * 64;
        bf16x8 ka0 = *(const bf16x8*)(kbase + (((0 + h + krow) & 7) * 8));
        bf16x8 ka1 = *(const bf16x8*)(kbase + (((2 + h + krow) & 7) * 8));
        bf16x8 ka2 = *(const bf16x8*)(kbase + (((4 + h + krow) & 7) * 8));
        bf16x8 ka3 = *(const bf16x8*)(kbase + (((6 + h + krow) & 7) * 8));
        __builtin_amdgcn_s_setprio(1);
        f32x16 st = __builtin_amdgcn_mfma_f32_32x32x16_bf16(ka0, qb[0], fz, 0, 0, 0);
        st = __builtin_amdgcn_mfma_f32_32x32x16_bf16(ka1, qb[1], st, 0, 0, 0);
        st = __builtin_amdgcn_mfma_f32_32x32x16_bf16(ka2, qb[2], st, 0, 0, 0);
        st = __builtin_amdgcn_mfma_f32_32x32x16_bf16(ka3, qb[3], st, 0, 0, 0);
        __builtin_amdgcn_s_setprio(0);
        return st;
    };

    // softmax (exp2+pack) of a PREVIOUS tile's st, then its PV MFMAs.
    auto SMPV = [&](const f32x16& st, const u16* vb) {
        u32 q32[8];
#pragma unroll
        for (int i = 0; i < 8; ++i) {
            float pe = EXP2(st[2 * i]);
            float po = EXP2(st[2 * i + 1]);
            q32[i] = __builtin_amdgcn_perm(fbits(po), fbits(pe), 0x07060302u);
        }
        union { u32 u[4]; bf16x8 v; } pf0, pf1;
#pragma unroll
        for (int i = 0; i < 4; ++i) { pf0.u[i] = q32[i]; pf1.u[i] = q32[4 + i]; }
        __builtin_amdgcn_s_setprio(1);
#pragma unroll
        for (int s2 = 0; s2 < 2; ++s2) {
            const int c = 4 * wk + 2 * s2 + h;
            bf16x8 vb0 = *(const bf16x8*)(vb + l31 * 64 + (((c + l31) & 7) * 8));
            bf16x8 vb1 = *(const bf16x8*)(vb + (32 + l31) * 64 + (((c + 32 + l31) & 7) * 8));
            const bf16x8 pv = s2 ? pf1.v : pf0.v;
            o0  = __builtin_amdgcn_mfma_f32_32x32x16_bf16(pv, vb0, o0, 0, 0, 0);
            o1  = __builtin_amdgcn_mfma_f32_32x32x16_bf16(pv, vb1, o1, 0, 0, 0);
            lac = __builtin_amdgcn_mfma_f32_32x32x16_bf16(pv, ones, lac, 0, 0, 0);
        }
        __builtin_amdgcn_s_setprio(0);
    };

    // ---- T15 ping-pong pipeline over 64 tiles ----
    u16 *kA = &k_lds[0][0], *kB = &k_lds[1][0], *kC = &k_lds[2][0];
    u16 *vA = &v_lds[0][0], *vB = &v_lds[1][0], *vC = &v_lds[2][0];

    SK(kA);                 // K tile 0
    SV(vA);                 // V tile 0
    SK(kB);                 // K tile 1
    asm volatile("s_waitcnt vmcnt(4)" ::: "memory");   // drain S_K(0)
    __builtin_amdgcn_s_barrier();
    f32x16 stA = QK(kA);    // st of tile 0
    SV(vB);                 // V tile 1
    f32x16 stB;

    for (int i = 0; i < 31; ++i) {
        // phase T = 2i: QK(T+1), softmax+PV(T)
        SK(kC);
        asm volatile("s_waitcnt vmcnt(4)" ::: "memory");
        __builtin_amdgcn_s_barrier();
        stB = QK(kB);
        SMPV(stA, vA);
        SV(vC);
        { u16* tt = kA; kA = kB; kB = kC; kC = tt; }
        { u16* tt = vA; vA = vB; vB = vC; vC = tt; }
        // phase T = 2i+1
        SK(kC);
        asm volatile("s_waitcnt vmcnt(4)" ::: "memory");
        __builtin_amdgcn_s_barrier();
        stA = QK(kB);
        SMPV(stB, vA);
        SV(vC);
        { u16* tt = kA; kA = kB; kB = kC; kC = tt; }
        { u16* tt = vA; vA = vB; vB = vC; vC = tt; }
    }
    // phase 62: no more K stages; drain S_V(62)+S_K(63), keep S_V(63) in flight
    asm volatile("s_waitcnt vmcnt(2)" ::: "memory");
    __builtin_amdgcn_s_barrier();
    stB = QK(kB);           // tile 63
    SMPV(stA, vA);          // tile 62
    { u16* tt = kA; kA = kB; kB = kC; kC = tt; }
    { u16* tt = vA; vA = vB; vB = vC; vC = tt; }
    // phase 63: drain everything
    asm volatile("s_waitcnt vmcnt(0)" ::: "memory");
    __builtin_amdgcn_s_barrier();
    SMPV(stB, vA);          // tile 63
    // buffers are about to be reused as reduction scratch by other waves
    __syncthreads();

    // publish l per q-row (lac is lane-uniform along cols: col=n of ones)
    if (l31 == 0) {
#pragma unroll
        for (int r = 0; r < 16; ++r) {
            int row = (r & 3) + 8 * (r >> 2) + 4 * h;
            l_red[wq][wk][row] = lac[r];
        }
    }
    // O cross-wk reduce via LDS scratch (qh0 -> k_lds, qh1 -> v_lds)
    float* scr = (wq == 0) ? (float*)&k_lds[0][0] : (float*)&v_lds[0][0];
    if (wk == 1) {
#pragma unroll
        for (int r = 0; r < 16; ++r) {
            int row = (r & 3) + 8 * (r >> 2) + 4 * h;
            scr[row * 64 + l31]      = o0[r];
            scr[row * 64 + 32 + l31] = o1[r];
        }
    }
    __syncthreads();
    if (wk == 0) {
#pragma unroll
        for (int r = 0; r < 16; ++r) {
            int row = (r & 3) + 8 * (r >> 2) + 4 * h;
            float lt   = l_red[wq][0][row] + l_red[wq][1][row];
            float invl = 1.0f / lt;
            float s0 = o0[r] + scr[row * 64 + l31];
            float s1 = o1[r] + scr[row * 64 + 32 + l31];
            size_t gr = (size_t)(q0 + row) * 768 + head * 64;
            out[gr + l31]      = f2bf(s0 * invl);
            out[gr + 32 + l31] = f2bf(s1 * invl);
        }
    }
}

extern "C" void kernel_launch(void* const* d_in, const int* in_sizes, int n_in,
                              void* d_out, int out_size, void* d_ws, size_t ws_size,
                              hipStream_t stream) {
    const int SX = SEQ * DIM;

    u16* base   = (u16*)d_ws;
    u16* xb     = base;                               // [SEQ][DIM] bf16
    u16* bqkvb  = xb + SX;
    u16* bprojb = bqkvb + NQKV;
    u16* wqkvT  = bprojb + DIM;                       // [NQKV][DIM]
    u16* wprojT = wqkvT + (size_t)NQKV * DIM;         // [DIM][DIM]
    u16* qkb    = wprojT + (size_t)DIM * DIM;         // [SEQ][1536] Q(scaled)|K
    u16* vtb    = qkb + (size_t)SEQ * 1536;           // [H][64][SEQ] V^T (sigma keys)
    u16* attnb  = xb;                                 // reuse x region

    prep<<<776, 256, 0, stream>>>(
        d_in[0], d_in[1], d_in[2], d_in[3], d_in[4], base, wqkvT, wprojT);
    gemm128<1, 64, 128><<<dim3(NQKV / 128, SEQ / 64), 256, 0, stream>>>(
        xb, wqkvT, bqkvb, qkb, nullptr, vtb, (const u32*)d_in[0],
        SEQ, NQKV, DIM);
    attn_kernel<<<dim3(SEQ / 64, HEADS), 256, 0, stream>>>(qkb, vtb, attnb);
    gemm128<0, 128, 128><<<dim3(DIM / 128, SEQ / 128), 256, 0, stream>>>(
        attnb, wprojT, bprojb, (u16*)d_out, (float*)d_out, nullptr,
        (const u32*)d_in[0], SEQ, DIM, DIM);
}

// Round 13
// 190.184 us; speedup vs baseline: 1.0849x; 1.0849x over previous
//
#include <hip/hip_runtime.h>
#include <hip/hip_bf16.h>

#define SEQ   4096
#define DIM   768
#define HEADS 12
#define NQKV  2304
// Q pre-scaled by 0.125*log2(e) in QKV epilogue -> p = 2^st = exp(score/8)
#define QSCALE 0.18033688011f

#if __has_builtin(__builtin_amdgcn_exp2f)
#define EXP2(x) __builtin_amdgcn_exp2f(x)
#else
#define EXP2(x) __expf((x) * 0.69314718056f)
#endif

typedef __bf16 bf16_t;
typedef bf16_t bf16x8 __attribute__((ext_vector_type(8)));
typedef float  f32x4  __attribute__((ext_vector_type(4)));
typedef float  f32x16 __attribute__((ext_vector_type(16)));
typedef unsigned short u16;
typedef unsigned int   u32;

static __device__ __forceinline__ float bf2f(u16 v) {
    union { float f; unsigned u; } x; x.u = ((unsigned)v) << 16; return x.f;
}
static __device__ __forceinline__ u16 f2bf(float f) {
    union { float f; unsigned u; } x; x.f = f;
    unsigned r = x.u + 0x7fff + ((x.u >> 16) & 1);   // RNE
    return (u16)(r >> 16);
}
static __device__ __forceinline__ u32 fbits(float f) {
    union { float f; unsigned u; } x; x.f = f; return x.u;
}
static __device__ __forceinline__ void gload_lds16(const u16* g, u16* l) {
    __builtin_amdgcn_global_load_lds(
        (const __attribute__((address_space(1))) unsigned int*)g,
        (__attribute__((address_space(3))) unsigned int*)l, 16, 0, 0);
}

// per-block dtype self-detection (x fp32 vs bf16)
static __device__ __forceinline__ int detect_f32(const u32* __restrict__ x) {
    int lane = threadIdx.x & 63;
    int cnt = 0;
#pragma unroll
    for (int i = 0; i < 8; ++i) {
        u32 w = x[lane * 8 + i];
        cnt += (((w >> 7) & 0xFF) >= 0x8F) ? 1 : 0;
    }
#pragma unroll
    for (int m = 1; m < 64; m <<= 1) cnt += __shfl_xor(cnt, m);
    return cnt >= 64;
}

// ---- fused prep: [0,432) transpose w_qkv; [432,576) transpose w_proj;
// [576,776) vectorized x conversion (+ biases on the first 3072 threads).
// R19: vectorized both paths (G13 — scalar bf16/f32 moves were ~2x cost):
// transpose loads via float4/ushort4, writeout packs 8 u16 -> 16B stores;
// x-conversion via float4 x2 -> bf16x8 (32B load / 16B store per lane).
// Element math identical (f2bf RNE per element) -> bit-identical output.
__global__ __launch_bounds__(256) void prep(
    const void* __restrict__ x, const void* __restrict__ wqkv,
    const void* __restrict__ bqkv, const void* __restrict__ wproj,
    const void* __restrict__ bproj,
    u16* __restrict__ cvt, u16* __restrict__ wqkvT, u16* __restrict__ wprojT)
{
    __shared__ u16 tile[64][65];
    const bool f32 = detect_f32((const u32*)x) != 0;
    const int b = blockIdx.x;
    const int t = threadIdx.x;

    if (b < 576) {
        const void* src; u16* dst; int K, N, tx, ty;
        if (b < 432) { src = wqkv; dst = wqkvT; K = DIM; N = NQKV; tx = b % 36; ty = b / 36; }
        else { int bb = b - 432; src = wproj; dst = wprojT; K = DIM; N = DIM; tx = bb % 12; ty = bb / 12; }
        const int k0 = ty * 64, n0 = tx * 64;
        // load 64x64 tile, 4 elems/lane/iter (16B f32 / 8B bf16 loads)
#pragma unroll
        for (int i = 0; i < 4; ++i) {
            int idx = i * 256 + t;              // 0..1023
            int r = idx >> 4, c4 = (idx & 15) * 4;
            size_t si = (size_t)(k0 + r) * N + n0 + c4;
            if (f32) {
                float4 v = *(const float4*)((const float*)src + si);
                tile[r][c4 + 0] = f2bf(v.x); tile[r][c4 + 1] = f2bf(v.y);
                tile[r][c4 + 2] = f2bf(v.z); tile[r][c4 + 3] = f2bf(v.w);
            } else {
                ushort4 v = *(const ushort4*)((const u16*)src + si);
                tile[r][c4 + 0] = v.x; tile[r][c4 + 1] = v.y;
                tile[r][c4 + 2] = v.z; tile[r][c4 + 3] = v.w;
            }
        }
        __syncthreads();
        // transposed writeout: pack 8 u16 along k -> one 16B store
#pragma unroll
        for (int i = 0; i < 2; ++i) {
            int idx = i * 256 + t;              // 0..511
            int r = idx >> 3, c0 = (idx & 7) * 8;
            union { u16 u[8]; bf16x8 v; } pk;
#pragma unroll
            for (int j = 0; j < 8; ++j) pk.u[j] = tile[c0 + j][r];
            *(bf16x8*)(dst + (size_t)(n0 + r) * K + k0 + c0) = pk.v;
        }
    } else {
        const int SX = SEQ * DIM;
        const int gid = (b - 576) * 256 + t;    // 0..51199
        for (int i = gid; i < SX / 8; i += 200 * 256) {
            if (f32) {
                float4 v0 = *((const float4*)x + (size_t)i * 2);
                float4 v1 = *((const float4*)x + (size_t)i * 2 + 1);
                union { u16 u[8]; bf16x8 v; } pk;
                pk.u[0] = f2bf(v0.x); pk.u[1] = f2bf(v0.y);
                pk.u[2] = f2bf(v0.z); pk.u[3] = f2bf(v0.w);
                pk.u[4] = f2bf(v1.x); pk.u[5] = f2bf(v1.y);
                pk.u[6] = f2bf(v1.z); pk.u[7] = f2bf(v1.w);
                *((bf16x8*)cvt + i) = pk.v;
            } else {
                *((bf16x8*)cvt + i) = *((const bf16x8*)x + i);
            }
        }
        if (gid < NQKV + DIM) {
            const void* s; int off;
            if (gid < NQKV) { s = bqkv;  off = gid; }
            else            { s = bproj; off = gid - NQKV; }
            cvt[SX + gid] = f32 ? f2bf(((const float*)s)[off]) : ((const u16*)s)[off];
        }
    }
}

// ---- m97-style GEMM, tile-size-templated: C[M,N] = A[M,K] @ BT[N,K]^T + bias[N]
// MODE 0: out dtype per self-detect (fp32 Cf / bf16 C0).
// MODE 1 (QKV): n<768 Q*QSCALE; n<1536 K; n>=1536 V -> coalesced
//   transpose-via-LDS into VT (sigma-permuted m).
// R14: counted-vmcnt 3-buffer K-loop (verified -21us). R15: T1 XCD remap.
// R19: both GEMMs at 128x128 — R10's best-measured config. Tile variations
// (R11 gemm2 64², R12 gemm1 64x128) were both noise-neutral: balance gains
// cancel per-tile efficiency losses. Tile space exhausted at this structure.
template<int MODE, int BM, int BN>
__global__ __launch_bounds__(256) void gemm128(
    const u16* __restrict__ A, const u16* __restrict__ BT, const u16* __restrict__ bias,
    u16* __restrict__ C0, float* __restrict__ Cf, u16* __restrict__ VT,
    const u32* __restrict__ xdet, int M, int N, int K)
{
    constexpr int WM  = BM / 2;            // per-wave output rows
    constexpr int WN  = BN / 2;            // per-wave output cols
    constexpr int NI  = WM / 16;           // m-frags per wave
    constexpr int NJ  = WN / 16;           // n-frags per wave
    constexpr int ARW = BM / 4;            // A stage rows per wave
    constexpr int BRW = BN / 4;            // B stage rows per wave
    constexpr int LPS = (BM + BN) / 64;    // gloads per stage per wave
    constexpr int TSTR = BM + 8;           // V-transpose LDS row stride (u16)

    __shared__ union SharedLds {
        struct { u16 a[3][BM * 32]; u16 b[3][BN * 32]; } s;     // 3-buffer staging
        u16 t[(MODE == 1) ? 128 * TSTR : 1];                     // V-transpose (MODE 1)
    } lds;

    const int t    = threadIdx.x;
    const int w    = t >> 6;
    const int lane = t & 63;
    const int l15  = lane & 15;
    const int quad = lane >> 4;
    const int wm   = w >> 1, wn = w & 1;

    // T1 XCD-bijective remap (nwg % 8 == 0 for all GEMM grids here)
    const int lin     = blockIdx.y * gridDim.x + blockIdx.x;
    const int cpx     = (gridDim.x * gridDim.y) >> 3;
    const int logical = (lin & 7) * cpx + (lin >> 3);
    const int m0 = (logical / gridDim.x) * BM;
    const int n0 = (logical % gridDim.x) * BN;

    const int kch = (lane & 3) * 8;
    const u16* asrc = A  + (size_t)(m0 + w * ARW + (lane >> 2)) * K + kch;
    const u16* bsrc = BT + (size_t)(n0 + w * BRW + (lane >> 2)) * K + kch;
    const int woffA = w * ARW * 32;
    const int woffB = w * BRW * 32;

    f32x4 acc[NI][NJ] = {};

    u16 *aA = lds.s.a[0], *aB = lds.s.a[1], *aC = lds.s.a[2];
    u16 *bA = lds.s.b[0], *bB = lds.s.b[1], *bC = lds.s.b[2];

    auto STAGE = [&](u16* ad, u16* bd) {
#pragma unroll
        for (int s = 0; s < BM / 64; ++s)
            gload_lds16(asrc + s * 16 * K, ad + woffA + s * 16 * 32);
#pragma unroll
        for (int s = 0; s < BN / 64; ++s)
            gload_lds16(bsrc + s * 16 * K, bd + woffB + s * 16 * 32);
        asrc += 32; bsrc += 32;
    };
    auto COMPUTE = [&](const u16* ab_, const u16* bb_) {
        const u16* ab = ab_ + (wm * WM + l15) * 32 + quad * 8;
        const u16* bb = bb_ + (wn * WN + l15) * 32 + quad * 8;
        bf16x8 af[NI], bfr[NJ];
#pragma unroll
        for (int i = 0; i < NI; ++i) af[i]  = *(const bf16x8*)(ab + i * 16 * 32);
#pragma unroll
        for (int j = 0; j < NJ; ++j) bfr[j] = *(const bf16x8*)(bb + j * 16 * 32);
#pragma unroll
        for (int i = 0; i < NI; ++i)
#pragma unroll
            for (int j = 0; j < NJ; ++j)
                acc[i][j] = __builtin_amdgcn_mfma_f32_16x16x32_bf16(af[i], bfr[j], acc[i][j], 0, 0, 0);
    };
    auto WAIT_LPS = [&]() {
        if constexpr (LPS == 4)      asm volatile("s_waitcnt vmcnt(4)" ::: "memory");
        else if constexpr (LPS == 3) asm volatile("s_waitcnt vmcnt(3)" ::: "memory");
        else                         asm volatile("s_waitcnt vmcnt(2)" ::: "memory");
    };

    const int NK = K >> 5;          // 24 for K=768
    STAGE(aA, bA);                  // tile 0
    STAGE(aB, bB);                  // tile 1
    for (int kt = 0; kt < NK - 2; ++kt) {
        // outstanding (oldest first): stage(kt)(LPS), stage(kt+1)(LPS)
        WAIT_LPS();                 // drain stage(kt)
        __builtin_amdgcn_s_barrier();
        STAGE(aC, bC);              // tile kt+2 (overwrites buffer read at kt-1)
        COMPUTE(aA, bA);            // tile kt
        { u16* tt = aA; aA = aB; aB = aC; aC = tt; }
        { u16* tt = bA; bA = bB; bB = bC; bC = tt; }
    }
    // tile NK-2: drain its stage, keep stage(NK-1) in flight
    WAIT_LPS();
    __builtin_amdgcn_s_barrier();
    COMPUTE(aA, bA);
    { u16* tt = aA; aA = aB; aB = aC; aC = tt; }
    { u16* tt = bA; bA = bB; bB = bC; bC = tt; }
    // tile NK-1: drain everything
    asm volatile("s_waitcnt vmcnt(0)" ::: "memory");
    __builtin_amdgcn_s_barrier();
    COMPUTE(aA, bA);

    if constexpr (MODE == 1) {
        if (n0 >= 1536) {
            // V transpose-via-LDS epilogue (coalesced stores). Staging buffers
            // are dead after the loop; lds.t aliases them — barrier first.
            __syncthreads();
#pragma unroll
            for (int i = 0; i < NI; ++i)
#pragma unroll
                for (int j = 0; j < NJ; ++j)
#pragma unroll
                    for (int r = 0; r < 4; ++r) {
                        int ml = wm * WM + i * 16 + quad * 4 + r;
                        int nl = wn * WN + j * 16 + l15;
                        int mpl = (ml & ~15) | (ml & 3) |
                                  (((ml >> 2) & 1) << 3) | (((ml >> 3) & 1) << 2);
                        float v = acc[i][j][r] + bf2f(bias[n0 + nl]);
                        lds.t[nl * TSTR + mpl] = f2bf(v);
                    }
            __syncthreads();
            // coalesced writeout: BM/8 lanes cover one row's BM*2B segment
            constexpr int LPR = BM / 8;         // lanes per row
            constexpr int RPP = 256 / LPR;      // rows per pass
            const int rr = t / LPR;
            const int mo = (t % LPR) * 8;
#pragma unroll
            for (int it = 0; it < 128 / RPP; ++it) {
                int nl = rr + it * RPP;
                *(bf16x8*)(VT + (size_t)(n0 - 1536 + nl) * SEQ + m0 + mo) =
                    *(const bf16x8*)(lds.t + nl * TSTR + mo);
            }
            return;
        }
    }

    bool outf32 = false;
    if (MODE == 0) outf32 = detect_f32(xdet) != 0;
#pragma unroll
    for (int i = 0; i < NI; ++i)
#pragma unroll
        for (int j = 0; j < NJ; ++j)
#pragma unroll
            for (int r = 0; r < 4; ++r) {
                int m = m0 + wm * WM + i * 16 + quad * 4 + r;
                int n = n0 + wn * WN + j * 16 + l15;
                float v = acc[i][j][r] + bf2f(bias[n]);
                if (MODE == 0) {
                    if (outf32) Cf[(size_t)m * N + n] = v;
                    else        C0[(size_t)m * N + n] = f2bf(v);
                } else {
                    // Q/K blocks only (V returned above)
                    float s = (n < 768) ? v * QSCALE : v;
                    C0[(size_t)m * 1536 + n] = f2bf(s);
                }
            }
}

// ---- Flash attention. Block = (64 q, head). 4 waves = (q-half wq) x (key-half wk).
// S^T = K x Q^T; sigma-permuted V^T makes S^T C-regs directly the PV A-fragment.
// p = 2^st (Q pre-scaled by QSCALE). Row-sums via ones-MFMA on the SAME
// packed/truncated P fragment (consistent normalization).
// Verified config (72-74us): launch_bounds(256,3) — register-limited at 3
// waves/SIMD (~76 arch VGPR + ~80 accumulator regs in the unified file);
// forcing 4 spills (R15: WRITE_SIZE 6MB->40MB). T15 st ping-pong, 3-buffer
// counted-vmcnt staging, XCD-bijective remap, s_setprio on MFMA clusters.
// Bank-conflict counter (~6.3M) verified benign: structural 4-way minimum on
// 128B rows (8 chunk positions / 32 rows); R2 halved the count, no speedup.
__global__ __launch_bounds__(256, 3) void attn_kernel(
    const u16* __restrict__ qk, const u16* __restrict__ vt, u16* __restrict__ out)
{
    __shared__ u16 k_lds[3][64 * 64];
    __shared__ u16 v_lds[3][64 * 64];
    __shared__ float l_red[2][2][32];   // [wq][wk][q]

    const int t    = threadIdx.x;
    const int w    = t >> 6;
    const int lane = t & 63;
    const int l31  = lane & 31;
    const int h    = lane >> 5;
    const int wq   = w & 1;
    const int wk   = w >> 1;

    // XCD-aware bijective remap (R1: FETCH 52MB -> 11.3MB).
    const int lin     = blockIdx.x + (blockIdx.y << 6);       // 0..767
    const int logical = (lin & 7) * 96 + (lin >> 3);
    const int head    = logical >> 6;
    const int q0      = (logical & 63) * 64 + wq * 32;

    // Q B-frags: q = q0+l31, d = h*8+16s+j (Q pre-scaled by QSCALE)
    const u16* qrow = qk + (size_t)(q0 + l31) * 1536 + head * 64 + h * 8;
    bf16x8 qb[4];
#pragma unroll
    for (int s = 0; s < 4; ++s) qb[s] = *(const bf16x8*)(qrow + 16 * s);

    bf16x8 ones;
#pragma unroll
    for (int j = 0; j < 8; ++j) ones[j] = (bf16_t)1.0f;

    const f32x16 fz = {};   // persistent zero C-operand for the first QK MFMA

    // staging: lane -> row 8w+(lane>>3), stored chunk lane&7 = logical chunk cs
    const int srow = 8 * w + (lane >> 3);
    const int cs   = ((lane & 7) - srow) & 7;
    const u16* kst0 = qk + 768 + head * 64 + (size_t)srow * 1536 + cs * 8;
    const u16* kst1 = kst0 + (size_t)32 * 1536;
    const u16* vst0 = vt + (size_t)head * 64 * SEQ + (size_t)srow * SEQ + cs * 8;
    const u16* vst1 = vst0 + (size_t)32 * SEQ;
    const int woff = 8 * w * 64;

    const int krow = 32 * wk + l31;

    f32x16 o0 = {}, o1 = {}, lac = {};

    auto SK = [&](u16* kd) {
        gload_lds16(kst0, kd + woff);
        gload_lds16(kst1, kd + woff + 32 * 64);
        kst0 += (size_t)64 * 1536;
        kst1 += (size_t)64 * 1536;
    };
    auto SV = [&](u16* vd) {
        gload_lds16(vst0, vd + woff);
        gload_lds16(vst1, vd + woff + 32 * 64);
        vst0 += 64;
        vst1 += 64;
    };

    // QK^T for one 64-key tile: 4 MFMA, returns S^T C-regs.
    auto QK = [&](const u16* kb) -> f32x16 {
        const u16* kbase = kb + krow * 64;
        bf16x8 ka0 = *(const bf16x8*)(kbase + (((0 + h + krow) & 7) * 8));
        bf16x8 ka1 = *(const bf16x8*)(kbase + (((2 + h + krow) & 7) * 8));
        bf16x8 ka2 = *(const bf16x8*)(kbase + (((4 + h + krow) & 7) * 8));
        bf16x8 ka3 = *(const bf16x8*)(kbase + (((6 + h + krow) & 7) * 8));
        __builtin_amdgcn_s_setprio(1);
        f32x16 st = __builtin_amdgcn_mfma_f32_32x32x16_bf16(ka0, qb[0], fz, 0, 0, 0);
        st = __builtin_amdgcn_mfma_f32_32x32x16_bf16(ka1, qb[1], st, 0, 0, 0);
        st = __builtin_amdgcn_mfma_f32_32x32x16_bf16(ka2, qb[2], st, 0, 0, 0);
        st = __builtin_amdgcn_mfma_f32_32x32x16_bf16(ka3, qb[3], st, 0, 0, 0);
        __builtin_amdgcn_s_setprio(0);
        return st;
    };

    // softmax (exp2+pack) of a PREVIOUS tile's st, then its PV MFMAs.
    auto SMPV = [&](const f32x16& st, const u16* vb) {
        u32 q32[8];
#pragma unroll
        for (int i = 0; i < 8; ++i) {
            float pe = EXP2(st[2 * i]);
            float po = EXP2(st[2 * i + 1]);
            q32[i] = __builtin_amdgcn_perm(fbits(po), fbits(pe), 0x07060302u);
        }
        union { u32 u[4]; bf16x8 v; } pf0, pf1;
#pragma unroll
        for (int i = 0; i < 4; ++i) { pf0.u[i] = q32[i]; pf1.u[i] = q32[4 + i]; }
        __builtin_amdgcn_s_setprio(1);
#pragma unroll
        for (int s2 = 0; s2 < 2; ++s2) {
            const int c = 4 * wk + 2 * s2 + h;
            bf16x8 vb0 = *(const bf16x8*)(vb + l31 * 64 + (((c + l31) & 7) * 8));
            bf16x8 vb1 = *(const bf16x8*)(vb + (32 + l31) * 64 + (((c + 32 + l31) & 7) * 8));
            const bf16x8 pv = s2 ? pf1.v : pf0.v;
            o0  = __builtin_amdgcn_mfma_f32_32x32x16_bf16(pv, vb0, o0, 0, 0, 0);
            o1  = __builtin_amdgcn_mfma_f32_32x32x16_bf16(pv, vb1, o1, 0, 0, 0);
            lac = __builtin_amdgcn_mfma_f32_32x32x16_bf16(pv, ones, lac, 0, 0, 0);
        }
        __builtin_amdgcn_s_setprio(0);
    };

    // ---- T15 ping-pong pipeline over 64 tiles ----
    u16 *kA = &k_lds[0][0], *kB = &k_lds[1][0], *kC = &k_lds[2][0];
    u16 *vA = &v_lds[0][0], *vB = &v_lds[1][0], *vC = &v_lds[2][0];

    SK(kA);                 // K tile 0
    SV(vA);                 // V tile 0
    SK(kB);                 // K tile 1
    asm volatile("s_waitcnt vmcnt(4)" ::: "memory");   // drain S_K(0)
    __builtin_amdgcn_s_barrier();
    f32x16 stA = QK(kA);    // st of tile 0
    SV(vB);                 // V tile 1
    f32x16 stB;

    for (int i = 0; i < 31; ++i) {
        // phase T = 2i: QK(T+1), softmax+PV(T)
        SK(kC);
        asm volatile("s_waitcnt vmcnt(4)" ::: "memory");
        __builtin_amdgcn_s_barrier();
        stB = QK(kB);
        SMPV(stA, vA);
        SV(vC);
        { u16* tt = kA; kA = kB; kB = kC; kC = tt; }
        { u16* tt = vA; vA = vB; vB = vC; vC = tt; }
        // phase T = 2i+1
        SK(kC);
        asm volatile("s_waitcnt vmcnt(4)" ::: "memory");
        __builtin_amdgcn_s_barrier();
        stA = QK(kB);
        SMPV(stB, vA);
        SV(vC);
        { u16* tt = kA; kA = kB; kB = kC; kC = tt; }
        { u16* tt = vA; vA = vB; vB = vC; vC = tt; }
    }
    // phase 62: no more K stages; drain S_V(62)+S_K(63), keep S_V(63) in flight
    asm volatile("s_waitcnt vmcnt(2)" ::: "memory");
    __builtin_amdgcn_s_barrier();
    stB = QK(kB);           // tile 63
    SMPV(stA, vA);          // tile 62
    { u16* tt = kA; kA = kB; kB = kC; kC = tt; }
    { u16* tt = vA; vA = vB; vB = vC; vC = tt; }
    // phase 63: drain everything
    asm volatile("s_waitcnt vmcnt(0)" ::: "memory");
    __builtin_amdgcn_s_barrier();
    SMPV(stB, vA);          // tile 63
    // buffers are about to be reused as reduction scratch by other waves
    __syncthreads();

    // publish l per q-row (lac is lane-uniform along cols: col=n of ones)
    if (l31 == 0) {
#pragma unroll
        for (int r = 0; r < 16; ++r) {
            int row = (r & 3) + 8 * (r >> 2) + 4 * h;
            l_red[wq][wk][row] = lac[r];
        }
    }
    // O cross-wk reduce via LDS scratch (qh0 -> k_lds, qh1 -> v_lds)
    float* scr = (wq == 0) ? (float*)&k_lds[0][0] : (float*)&v_lds[0][0];
    if (wk == 1) {
#pragma unroll
        for (int r = 0; r < 16; ++r) {
            int row = (r & 3) + 8 * (r >> 2) + 4 * h;
            scr[row * 64 + l31]      = o0[r];
            scr[row * 64 + 32 + l31] = o1[r];
        }
    }
    __syncthreads();
    if (wk == 0) {
#pragma unroll
        for (int r = 0; r < 16; ++r) {
            int row = (r & 3) + 8 * (r >> 2) + 4 * h;
            float lt   = l_red[wq][0][row] + l_red[wq][1][row];
            float invl = 1.0f / lt;
            float s0 = o0[r] + scr[row * 64 + l31];
            float s1 = o1[r] + scr[row * 64 + 32 + l31];
            size_t gr = (size_t)(q0 + row) * 768 + head * 64;
            out[gr + l31]      = f2bf(s0 * invl);
            out[gr + 32 + l31] = f2bf(s1 * invl);
        }
    }
}

extern "C" void kernel_launch(void* const* d_in, const int* in_sizes, int n_in,
                              void* d_out, int out_size, void* d_ws, size_t ws_size,
                              hipStream_t stream) {
    const int SX = SEQ * DIM;

    u16* base   = (u16*)d_ws;
    u16* xb     = base;                               // [SEQ][DIM] bf16
    u16* bqkvb  = xb + SX;
    u16* bprojb = bqkvb + NQKV;
    u16* wqkvT  = bprojb + DIM;                       // [NQKV][DIM]
    u16* wprojT = wqkvT + (size_t)NQKV * DIM;         // [DIM][DIM]
    u16* qkb    = wprojT + (size_t)DIM * DIM;         // [SEQ][1536] Q(scaled)|K
    u16* vtb    = qkb + (size_t)SEQ * 1536;           // [H][64][SEQ] V^T (sigma keys)
    u16* attnb  = xb;                                 // reuse x region

    prep<<<776, 256, 0, stream>>>(
        d_in[0], d_in[1], d_in[2], d_in[3], d_in[4], base, wqkvT, wprojT);
    gemm128<1, 128, 128><<<dim3(NQKV / 128, SEQ / 128), 256, 0, stream>>>(
        xb, wqkvT, bqkvb, qkb, nullptr, vtb, (const u32*)d_in[0],
        SEQ, NQKV, DIM);
    attn_kernel<<<dim3(SEQ / 64, HEADS), 256, 0, stream>>>(qkb, vtb, attnb);
    gemm128<0, 128, 128><<<dim3(DIM / 128, SEQ / 128), 256, 0, stream>>>(
        attnb, wprojT, bprojb, (u16*)d_out, (float*)d_out, nullptr,
        (const u32*)d_in[0], SEQ, DIM, DIM);
}